// Round 11
// baseline (180.839 us; speedup 1.0000x reference)
//
#include <hip/hip_runtime.h>
#include <math.h>

#define HH 1024
#define WW 1024
#define OUTW 58            // output columns per wave (64 lanes - 6 halo)
#define RPB 4              // output rows per WAVE (must be even: row-pair loop)
#define WPB 4              // waves per block (independent y-strips, no barrier)
#define OFF(i) ((i)*8 - (i)*((i)-1)/2)   // packed upper-tri row offset

// Round-4 lesson: forcing a VGPR cap below the working set -> 1.2 GB spill.
// Round-7/10 lesson + m69: gfx950 occupancy steps only at VGPR {64,128,256};
// allocator refuses the 256 bucket (spills or serializes at 128) unless the
// live set genuinely exceeds 128 AND waves_per_eu permits 1. Measured
// residency is ~1.3-1.6 waves/SIMD, so the 256-VGPR bucket is free here.
// Round-8 lesson: cross-lane ops (DPP/bpermute) never inside divergent flow.

// DPP move, bound_ctrl=1 (invalid lanes read 0)
template<int CTRL>
__device__ __forceinline__ float dpp0(float x) {
    return __int_as_float(
        __builtin_amdgcn_update_dpp(0, __float_as_int(x), CTRL, 0xf, 0xf, true));
}
// whole-wave shift right by 1 lane (crosses 16-lane row boundaries)
__device__ __forceinline__ float wshr1(float x) { return dpp0<0x138>(x); }

// fp32 reciprocal: v_rcp_f32 + 1 Newton step (~1ulp); LDL^T is sqrt-free
__device__ __forceinline__ float frcp_fast(float s) {
    float r = __builtin_amdgcn_rcpf(s);
    return r * fmaf(-s, r, 2.0f);
}

__global__ __launch_bounds__(WPB * 64)
__attribute__((amdgpu_waves_per_eu(1, 8)))
void ls_sep_kernel(
    const float* __restrict__ inp,    // [3,H,W]
    const float* __restrict__ dep,    // [1,H,W]
    const float* __restrict__ alb,    // [3,H,W]
    const float* __restrict__ nrm,    // [3,H,W]
    float* __restrict__ out)          // [3,H,W]
{
    const int L  = threadIdx.x & 63;          // lane 0..63
    const int wv = threadIdx.x >> 6;          // wave 0..3 (independent y-strip)
    const int HW = HH * WW;
    // lane L sums column x; its horizontal window (x-6..x) is centered at x-3
    const int x  = OUTW * blockIdx.x - 3 + L;
    const int y0 = (RPB * WPB) * blockIdx.y + RPB * wv;
    const int px = x - 3;                     // output pixel column for this lane

    const int xc    = min(max(x, 0), WW - 1);
    const float xok = (x >= 0 && x < WW) ? 1.f : 0.f;

    float C[60];                              // running column sums (7 rows in y)
    #pragma unroll
    for (int k = 0; k < 60; k++) C[k] = 0.f;

    auto acc_row = [&](int yy, float sgn) {
        const int yc = min(max(yy, 0), HH - 1);
        const float ok = (yy >= 0 && yy < HH) ? xok : 0.f;
        const int p = yc * WW + xc;
        float fv[8], yv[3];
        fv[0] = 1.f;
        fv[1] = dep[p];
        fv[2] = alb[p];
        fv[3] = alb[p + HW];
        fv[4] = alb[p + 2 * HW];
        fv[5] = nrm[p];
        fv[6] = nrm[p + HW];
        fv[7] = nrm[p + 2 * HW];
        yv[0] = inp[p];
        yv[1] = inp[p + HW];
        yv[2] = inp[p + 2 * HW];
        const float s = sgn * ok;
        float fs[8];
        #pragma unroll
        for (int i = 0; i < 8; i++) fs[i] = fv[i] * s;
        int k = 0;
        #pragma unroll
        for (int i = 0; i < 8; i++)
            #pragma unroll
            for (int j = i; j < 8; j++) { C[k] = fmaf(fs[i], fv[j], C[k]); k++; }
        #pragma unroll
        for (int i = 0; i < 8; i++)
            #pragma unroll
            for (int c = 0; c < 3; c++)
                C[36 + i * 3 + c] = fmaf(fs[i], yv[c], C[36 + i * 3 + c]);
    };

    // preload rows y0-4 .. y0+2 (first pair-iter does add(y0+3), sub(y0-4))
    #pragma unroll 1
    for (int yy = y0 - 4; yy < y0 + 3; yy++) acc_row(yy, 1.f);

    const int idxm4 = ((L - 4) & 63) << 2;    // bpermute byte index for lane L-4
    const int pxc = min(max(px, 0), WW - 1);
    const bool do_store = (L >= 6) && (px < WW);

    // horizontal 7-tap over lanes L-6..L; MUST be called by all 64 lanes
    auto htap = [&](float xv) -> float {
        const float w1 = wshr1(xv);           // C(L-1)
        const float t1 = xv + w1;             // L-1..L
        const float w2 = wshr1(w1);           // C(L-2)
        const float t3 = t1 + w2;             // L-2..L
        const float w3 = wshr1(w2);           // C(L-3)
        const float t2 = t3 + w3;             // L-3..L
        const float pm = __int_as_float(
            __builtin_amdgcn_ds_bpermute(idxm4, __float_as_int(t3))); // L-6..L-4
        return t2 + pm;
    };

    // ---- row-PAIR loop: two independent factor/solve chains interleaved
    //      at source level (innermost loop over pair index p) ----
    #pragma unroll 1
    for (int y = y0; y < y0 + RPB; y += 2) {
        float W[2][36], cf[2][8], Y0[24];

        // row y state
        acc_row(y + 3, 1.f);
        acc_row(y - 4, -1.f);
        #pragma unroll
        for (int k = 0; k < 36; k++) W[0][k] = htap(C[k]);
        #pragma unroll
        for (int k = 0; k < 24; k++) Y0[k] = htap(C[36 + k]);   // AtY(row y): tap
                                                                // BEFORE slide
        {
            const int pc = y * WW + pxc;
            cf[0][0] = 1.f;
            cf[0][1] = dep[pc];
            cf[0][2] = alb[pc]; cf[0][3] = alb[pc + HW]; cf[0][4] = alb[pc + 2 * HW];
            cf[0][5] = nrm[pc]; cf[0][6] = nrm[pc + HW]; cf[0][7] = nrm[pc + 2 * HW];
        }

        // row y+1 state
        acc_row(y + 4, 1.f);
        acc_row(y - 3, -1.f);
        #pragma unroll
        for (int k = 0; k < 36; k++) W[1][k] = htap(C[k]);
        {
            const int pc = (y + 1) * WW + pxc;
            cf[1][0] = 1.f;
            cf[1][1] = dep[pc];
            cf[1][2] = alb[pc]; cf[1][3] = alb[pc + HW]; cf[1][4] = alb[pc + 2 * HW];
            cf[1][5] = nrm[pc]; cf[1][6] = nrm[pc + HW]; cf[1][7] = nrm[pc + 2 * HW];
        }

        #pragma unroll
        for (int p = 0; p < 2; p++)
            #pragma unroll
            for (int i = 0; i < 8; i++) W[p][OFF(i)] += 1.0e-4f;

        // ---- two fp32 LDL^T factorizations, lock-step interleaved ----
        float idv[2][8];
        #pragma unroll
        for (int i = 0; i < 8; i++) {
            #pragma unroll
            for (int k = 0; k < i; k++) {
                #pragma unroll
                for (int p = 0; p < 2; p++) {
                    const float c = W[p][OFF(k) + i - k] * idv[p][k];
                    #pragma unroll
                    for (int j = i; j < 8; j++)
                        W[p][OFF(i) + j - i] =
                            fmaf(-c, W[p][OFF(k) + j - k], W[p][OFF(i) + j - i]);
                }
            }
            #pragma unroll
            for (int p = 0; p < 2; p++)
                idv[p][i] = frcp_fast(W[p][OFF(i)]);
        }

        // forward substitution, interleaved
        float vt[2][8];
        #pragma unroll
        for (int i = 0; i < 8; i++) {
            #pragma unroll
            for (int p = 0; p < 2; p++) {
                float s = cf[p][i];
                #pragma unroll
                for (int k = 0; k < i; k++)
                    s = fmaf(-W[p][OFF(k) + i - k], vt[p][k], s);
                vt[p][i] = s * idv[p][i];
            }
        }
        // back substitution, interleaved
        float w[2][8];
        #pragma unroll
        for (int i = 7; i >= 0; i--) {
            #pragma unroll
            for (int p = 0; p < 2; p++) {
                float t = 0.f;
                #pragma unroll
                for (int j = i + 1; j < 8; j++)
                    t = fmaf(W[p][OFF(i) + j - i], w[p][j], t);
                w[p][i] = fmaf(-idv[p][i], t, vt[p][i]);
            }
        }

        // ---- outputs: row y from saved Y0 taps; row y+1 taps C (current
        //      state = window y+1). All lanes execute (htap cross-lane). ----
        float r0[3], r1[3];
        #pragma unroll
        for (int c = 0; c < 3; c++) {
            float a = 0.f;
            #pragma unroll
            for (int i = 0; i < 8; i++)
                a = fmaf(w[0][i], Y0[i * 3 + c], a);
            r0[c] = a;
        }
        #pragma unroll
        for (int c = 0; c < 3; c++) {
            float a = 0.f;
            #pragma unroll
            for (int i = 0; i < 8; i++)
                a = fmaf(w[1][i], htap(C[36 + i * 3 + c]), a);
            r1[c] = a;
        }

        if (do_store) {
            const int p0 = y * WW + px;
            const int p1 = (y + 1) * WW + px;
            #pragma unroll
            for (int c = 0; c < 3; c++) {
                out[c * HW + p0] = r0[c];
                out[c * HW + p1] = r1[c];
            }
        }
    }
}

extern "C" void kernel_launch(void* const* d_in, const int* in_sizes, int n_in,
                              void* d_out, int out_size, void* d_ws, size_t ws_size,
                              hipStream_t stream) {
    const float* inp = (const float*)d_in[0];
    const float* dep = (const float*)d_in[1];
    const float* alb = (const float*)d_in[2];
    const float* nrm = (const float*)d_in[3];
    float* out = (float*)d_out;
    dim3 grid((WW + OUTW - 1) / OUTW, HH / (RPB * WPB));   // 18 x 64, 256-thr blocks
    ls_sep_kernel<<<grid, dim3(WPB * 64), 0, stream>>>(inp, dep, alb, nrm, out);
}

// Round 12
// 127.595 us; speedup vs baseline: 1.4173x; 1.4173x over previous
//
#include <hip/hip_runtime.h>
#include <math.h>

#define HH 1024
#define WW 1024
#define OUTW 58            // output columns per wave (64 lanes - 6 halo)
#define RPB 4              // output rows per WAVE (vertical slide length)
#define WPB 4              // waves per block (independent y-strips, no barrier)
#define OFF(i) ((i)*8 - (i)*((i)-1)/2)   // packed upper-tri row offset

// Hard-won constraints (rounds 4/7/10/11):
//  - VGPR bucket MUST stay 128: resident waves scale with the bucket cap
//    (occ% 34/16/9.7 at VGPR 64/128/216) — buying regs for ILP sells waves
//    and VALUBusy DROPS (r11: 49->31%). Peak live floats <= ~120.
//  - Allocator at 128 prefers spilling over the 256 bucket (r7: 40 MB
//    scratch). Watch WRITE_SIZE ~13.5 MB as the no-spill invariant.
//  - Cross-lane ops (DPP/bpermute) never inside divergent flow (r8).

// DPP move, bound_ctrl=1 (invalid lanes read 0)
template<int CTRL>
__device__ __forceinline__ float dpp0(float x) {
    return __int_as_float(
        __builtin_amdgcn_update_dpp(0, __float_as_int(x), CTRL, 0xf, 0xf, true));
}
// whole-wave shift right by 1 lane (crosses 16-lane row boundaries)
__device__ __forceinline__ float wshr1(float x) { return dpp0<0x138>(x); }

// fp32 reciprocal: v_rcp_f32 + 1 Newton step (~1ulp); LDL^T is sqrt-free
__device__ __forceinline__ float frcp_fast(float s) {
    float r = __builtin_amdgcn_rcpf(s);
    return r * fmaf(-s, r, 2.0f);
}

__global__ __launch_bounds__(WPB * 64, 2) void ls_sep_kernel(
    const float* __restrict__ inp,    // [3,H,W]
    const float* __restrict__ dep,    // [1,H,W]
    const float* __restrict__ alb,    // [3,H,W]
    const float* __restrict__ nrm,    // [3,H,W]
    float* __restrict__ out)          // [3,H,W]
{
    const int L  = threadIdx.x & 63;          // lane 0..63
    const int wv = threadIdx.x >> 6;          // wave 0..3 (independent y-strip)
    const int HW = HH * WW;
    // lane L sums column x; its horizontal window (x-6..x) is centered at x-3
    const int x  = OUTW * blockIdx.x - 3 + L;
    const int y0 = (RPB * WPB) * blockIdx.y + RPB * wv;
    const int px = x - 3;                     // output pixel column for this lane

    const int xc    = min(max(x, 0), WW - 1);
    const float xok = (x >= 0 && x < WW) ? 1.f : 0.f;

    float C[60];                              // running column sums (7 rows in y)
    #pragma unroll
    for (int k = 0; k < 60; k++) C[k] = 0.f;

    auto acc_row = [&](int yy, float sgn) {
        const int yc = min(max(yy, 0), HH - 1);
        const float ok = (yy >= 0 && yy < HH) ? xok : 0.f;
        const int p = yc * WW + xc;
        float fv[8], yv[3];
        fv[0] = 1.f;
        fv[1] = dep[p];
        fv[2] = alb[p];
        fv[3] = alb[p + HW];
        fv[4] = alb[p + 2 * HW];
        fv[5] = nrm[p];
        fv[6] = nrm[p + HW];
        fv[7] = nrm[p + 2 * HW];
        yv[0] = inp[p];
        yv[1] = inp[p + HW];
        yv[2] = inp[p + 2 * HW];
        const float s = sgn * ok;
        float fs[8];
        #pragma unroll
        for (int i = 0; i < 8; i++) fs[i] = fv[i] * s;
        int k = 0;
        #pragma unroll
        for (int i = 0; i < 8; i++)
            #pragma unroll
            for (int j = i; j < 8; j++) { C[k] = fmaf(fs[i], fv[j], C[k]); k++; }
        #pragma unroll
        for (int i = 0; i < 8; i++)
            #pragma unroll
            for (int c = 0; c < 3; c++)
                C[36 + i * 3 + c] = fmaf(fs[i], yv[c], C[36 + i * 3 + c]);
    };

    // preload rows y0-4 .. y0+2 (loop body does add(y+3), sub(y-4))
    #pragma unroll 1
    for (int yy = y0 - 4; yy < y0 + 3; yy++) acc_row(yy, 1.f);

    const int idxm4 = ((L - 4) & 63) << 2;    // bpermute byte index for lane L-4
    const int pxc = min(max(px, 0), WW - 1);
    const bool do_store = (L >= 6) && (px < WW);

    // Batched horizontal 7-tap over lanes L-6..L for 12 values at once:
    // the 12 independent ds_bpermute ops issue back-to-back so their
    // lgkmcnt waits amortize 12x (round-9 paid ~60 serial LDS-pipe waits
    // per row). MUST be called by all 64 lanes (cross-lane inside).
    auto htap12 = [&](int base, float* dst) {
        float t2a[12];
        int pma[12];
        #pragma unroll
        for (int j = 0; j < 12; j++) {
            const float xv = C[base + j];
            const float w1 = wshr1(xv);       // C(L-1)
            const float t1 = xv + w1;         // L-1..L
            const float w2 = wshr1(w1);       // C(L-2)
            const float t3 = t1 + w2;         // L-2..L
            const float w3 = wshr1(w2);       // C(L-3)
            t2a[j] = t3 + w3;                 // L-3..L
            pma[j] = __builtin_amdgcn_ds_bpermute(idxm4, __float_as_int(t3));
        }
        #pragma unroll
        for (int j = 0; j < 12; j++)
            dst[j] = t2a[j] + __int_as_float(pma[j]);   // + (L-6..L-4)
    };

    #pragma unroll 1
    for (int y = y0; y < y0 + RPB; y++) {
        acc_row(y + 3, 1.f);
        acc_row(y - 4, -1.f);

        // center-pixel features EARLY: their global-load latency hides
        // under the htap arithmetic below instead of stalling the solve
        const int pc = y * WW + pxc;
        float cf[8];
        cf[0] = 1.f;
        cf[1] = dep[pc];
        cf[2] = alb[pc]; cf[3] = alb[pc + HW]; cf[4] = alb[pc + 2 * HW];
        cf[5] = nrm[pc]; cf[6] = nrm[pc + HW]; cf[7] = nrm[pc + 2 * HW];

        // ---- horizontal taps for AtA (AtY deferred past the solve) ----
        float W[36];
        htap12(0,  &W[0]);
        htap12(12, &W[12]);
        htap12(24, &W[24]);
        #pragma unroll
        for (int i = 0; i < 8; i++) W[OFF(i)] += 1.0e-4f;

        // ---- fp32 LDL^T (sqrt-free). W row i keeps R_ij = d_i*U_ij ----
        float idv[8];
        #pragma unroll
        for (int i = 0; i < 8; i++) {
            #pragma unroll
            for (int k = 0; k < i; k++) {
                const float c = W[OFF(k) + i - k] * idv[k];   // U_ki
                #pragma unroll
                for (int j = i; j < 8; j++)
                    W[OFF(i) + j - i] = fmaf(-c, W[OFF(k) + j - k], W[OFF(i) + j - i]);
            }
            idv[i] = frcp_fast(W[OFF(i)]);    // 1/d_i
        }

        // forward: vt_i = idv_i * (cf_i - sum_{k<i} R_ki * vt_k)
        float vt[8];
        #pragma unroll
        for (int i = 0; i < 8; i++) {
            float s = cf[i];
            #pragma unroll
            for (int k = 0; k < i; k++)
                s = fmaf(-W[OFF(k) + i - k], vt[k], s);
            vt[i] = s * idv[i];
        }
        // back: w_i = vt_i - idv_i * sum_{j>i} R_ij * w_j
        float w[8];
        #pragma unroll
        for (int i = 7; i >= 0; i--) {
            float t = 0.f;
            #pragma unroll
            for (int j = i + 1; j < 8; j++)
                t = fmaf(W[OFF(i) + j - i], w[j], t);
            w[i] = fmaf(-idv[i], t, vt[i]);
        }

        // ---- deferred AtY taps (batched) + output dot products:
        //      ALL lanes execute; only the store is predicated ----
        float r[3] = {0.f, 0.f, 0.f};
        {
            float SY[12];
            htap12(36, SY);                   // AtY for i=0..3
            #pragma unroll
            for (int i = 0; i < 4; i++)
                #pragma unroll
                for (int c = 0; c < 3; c++)
                    r[c] = fmaf(w[i], SY[i * 3 + c], r[c]);
            htap12(48, SY);                   // AtY for i=4..7
            #pragma unroll
            for (int i = 0; i < 4; i++)
                #pragma unroll
                for (int c = 0; c < 3; c++)
                    r[c] = fmaf(w[i + 4], SY[i * 3 + c], r[c]);
        }

        if (do_store) {
            const int p = y * WW + px;
            #pragma unroll
            for (int c = 0; c < 3; c++)
                out[c * HW + p] = r[c];
        }
    }
}

extern "C" void kernel_launch(void* const* d_in, const int* in_sizes, int n_in,
                              void* d_out, int out_size, void* d_ws, size_t ws_size,
                              hipStream_t stream) {
    const float* inp = (const float*)d_in[0];
    const float* dep = (const float*)d_in[1];
    const float* alb = (const float*)d_in[2];
    const float* nrm = (const float*)d_in[3];
    float* out = (float*)d_out;
    dim3 grid((WW + OUTW - 1) / OUTW, HH / (RPB * WPB));   // 18 x 64, 256-thr blocks
    ls_sep_kernel<<<grid, dim3(WPB * 64), 0, stream>>>(inp, dep, alb, nrm, out);
}

// Round 13
// 126.078 us; speedup vs baseline: 1.4343x; 1.0120x over previous
//
#include <hip/hip_runtime.h>
#include <math.h>

#define HH 1024
#define WW 1024
#define OUTW 58            // output columns per wave (64 lanes - 6 halo)
#define RPB 2              // output rows per WAVE (scaling probe: 2x waves)
#define WPB 4              // waves per block (independent y-strips, no barrier)
#define OFF(i) ((i)*8 - (i)*((i)-1)/2)   // packed upper-tri row offset

// Hard-won constraints (rounds 4/7/10/11/12):
//  - VGPR bucket MUST stay 128: resident waves scale with the bucket cap
//    (occ% 34/16/9.7 at VGPR 64/128/216); regs-for-ILP sells waves and
//    VALUBusy DROPS (r11: 49->31%). Peak live floats <= ~120.
//  - Allocator at 128 prefers spilling over the 256 bucket (r7: 40 MB
//    scratch). Watch WRITE_SIZE ~13.5 MB as the no-spill invariant.
//  - Cross-lane ops (DPP/bpermute) never inside divergent flow (r8).
//  - bpermute batching is already done by the scheduler (r12 neutral).

// DPP move, bound_ctrl=1 (invalid lanes read 0)
template<int CTRL>
__device__ __forceinline__ float dpp0(float x) {
    return __int_as_float(
        __builtin_amdgcn_update_dpp(0, __float_as_int(x), CTRL, 0xf, 0xf, true));
}
// whole-wave shift right by 1 lane (crosses 16-lane row boundaries)
__device__ __forceinline__ float wshr1(float x) { return dpp0<0x138>(x); }

// fp32 reciprocal: v_rcp_f32 + 1 Newton step (~1ulp); LDL^T is sqrt-free
__device__ __forceinline__ float frcp_fast(float s) {
    float r = __builtin_amdgcn_rcpf(s);
    return r * fmaf(-s, r, 2.0f);
}

__global__ __launch_bounds__(WPB * 64, 2) void ls_sep_kernel(
    const float* __restrict__ inp,    // [3,H,W]
    const float* __restrict__ dep,    // [1,H,W]
    const float* __restrict__ alb,    // [3,H,W]
    const float* __restrict__ nrm,    // [3,H,W]
    float* __restrict__ out)          // [3,H,W]
{
    const int L  = threadIdx.x & 63;          // lane 0..63
    const int wv = threadIdx.x >> 6;          // wave 0..3 (independent y-strip)
    const int HW = HH * WW;
    // lane L sums column x; its horizontal window (x-6..x) is centered at x-3
    const int x  = OUTW * blockIdx.x - 3 + L;
    const int y0 = (RPB * WPB) * blockIdx.y + RPB * wv;
    const int px = x - 3;                     // output pixel column for this lane

    const int xc    = min(max(x, 0), WW - 1);
    const float xok = (x >= 0 && x < WW) ? 1.f : 0.f;

    float C[60];                              // running column sums (7 rows in y)
    #pragma unroll
    for (int k = 0; k < 60; k++) C[k] = 0.f;

    auto acc_row = [&](int yy, float sgn) {
        const int yc = min(max(yy, 0), HH - 1);
        const float ok = (yy >= 0 && yy < HH) ? xok : 0.f;
        const int p = yc * WW + xc;
        float fv[8], yv[3];
        fv[0] = 1.f;
        fv[1] = dep[p];
        fv[2] = alb[p];
        fv[3] = alb[p + HW];
        fv[4] = alb[p + 2 * HW];
        fv[5] = nrm[p];
        fv[6] = nrm[p + HW];
        fv[7] = nrm[p + 2 * HW];
        yv[0] = inp[p];
        yv[1] = inp[p + HW];
        yv[2] = inp[p + 2 * HW];
        const float s = sgn * ok;
        float fs[8];
        #pragma unroll
        for (int i = 0; i < 8; i++) fs[i] = fv[i] * s;
        int k = 0;
        #pragma unroll
        for (int i = 0; i < 8; i++)
            #pragma unroll
            for (int j = i; j < 8; j++) { C[k] = fmaf(fs[i], fv[j], C[k]); k++; }
        #pragma unroll
        for (int i = 0; i < 8; i++)
            #pragma unroll
            for (int c = 0; c < 3; c++)
                C[36 + i * 3 + c] = fmaf(fs[i], yv[c], C[36 + i * 3 + c]);
    };

    // preload rows y0-4 .. y0+2 (loop body does add(y+3), sub(y-4))
    #pragma unroll 1
    for (int yy = y0 - 4; yy < y0 + 3; yy++) acc_row(yy, 1.f);

    const int idxm4 = ((L - 4) & 63) << 2;    // bpermute byte index for lane L-4
    const int pxc = min(max(px, 0), WW - 1);
    const bool do_store = (L >= 6) && (px < WW);

    // Batched horizontal 7-tap over lanes L-6..L for 12 values at once.
    // MUST be called by all 64 lanes (cross-lane inside).
    auto htap12 = [&](int base, float* dst) {
        float t2a[12];
        int pma[12];
        #pragma unroll
        for (int j = 0; j < 12; j++) {
            const float xv = C[base + j];
            const float w1 = wshr1(xv);       // C(L-1)
            const float t1 = xv + w1;         // L-1..L
            const float w2 = wshr1(w1);       // C(L-2)
            const float t3 = t1 + w2;         // L-2..L
            const float w3 = wshr1(w2);       // C(L-3)
            t2a[j] = t3 + w3;                 // L-3..L
            pma[j] = __builtin_amdgcn_ds_bpermute(idxm4, __float_as_int(t3));
        }
        #pragma unroll
        for (int j = 0; j < 12; j++)
            dst[j] = t2a[j] + __int_as_float(pma[j]);   // + (L-6..L-4)
    };

    #pragma unroll 1
    for (int y = y0; y < y0 + RPB; y++) {
        acc_row(y + 3, 1.f);
        acc_row(y - 4, -1.f);

        // center-pixel features EARLY: global-load latency hides under taps
        const int pc = y * WW + pxc;
        float cf[8];
        cf[0] = 1.f;
        cf[1] = dep[pc];
        cf[2] = alb[pc]; cf[3] = alb[pc + HW]; cf[4] = alb[pc + 2 * HW];
        cf[5] = nrm[pc]; cf[6] = nrm[pc + HW]; cf[7] = nrm[pc + 2 * HW];

        // ---- horizontal taps for AtA (AtY deferred past the solve) ----
        float W[36];
        htap12(0,  &W[0]);
        htap12(12, &W[12]);
        htap12(24, &W[24]);
        #pragma unroll
        for (int i = 0; i < 8; i++) W[OFF(i)] += 1.0e-4f;

        // ---- fp32 LDL^T (sqrt-free). W row i keeps R_ij = d_i*U_ij ----
        float idv[8];
        #pragma unroll
        for (int i = 0; i < 8; i++) {
            #pragma unroll
            for (int k = 0; k < i; k++) {
                const float c = W[OFF(k) + i - k] * idv[k];   // U_ki
                #pragma unroll
                for (int j = i; j < 8; j++)
                    W[OFF(i) + j - i] = fmaf(-c, W[OFF(k) + j - k], W[OFF(i) + j - i]);
            }
            idv[i] = frcp_fast(W[OFF(i)]);    // 1/d_i
        }

        // forward: vt_i = idv_i * (cf_i - sum_{k<i} R_ki * vt_k)
        float vt[8];
        #pragma unroll
        for (int i = 0; i < 8; i++) {
            float s = cf[i];
            #pragma unroll
            for (int k = 0; k < i; k++)
                s = fmaf(-W[OFF(k) + i - k], vt[k], s);
            vt[i] = s * idv[i];
        }
        // back: w_i = vt_i - idv_i * sum_{j>i} R_ij * w_j
        float w[8];
        #pragma unroll
        for (int i = 7; i >= 0; i--) {
            float t = 0.f;
            #pragma unroll
            for (int j = i + 1; j < 8; j++)
                t = fmaf(W[OFF(i) + j - i], w[j], t);
            w[i] = fmaf(-idv[i], t, vt[i]);
        }

        // ---- deferred AtY taps (batched) + output dot products:
        //      ALL lanes execute; only the store is predicated ----
        float r[3] = {0.f, 0.f, 0.f};
        {
            float SY[12];
            htap12(36, SY);                   // AtY for i=0..3
            #pragma unroll
            for (int i = 0; i < 4; i++)
                #pragma unroll
                for (int c = 0; c < 3; c++)
                    r[c] = fmaf(w[i], SY[i * 3 + c], r[c]);
            htap12(48, SY);                   // AtY for i=4..7
            #pragma unroll
            for (int i = 0; i < 4; i++)
                #pragma unroll
                for (int c = 0; c < 3; c++)
                    r[c] = fmaf(w[i + 4], SY[i * 3 + c], r[c]);
        }

        if (do_store) {
            const int p = y * WW + px;
            #pragma unroll
            for (int c = 0; c < 3; c++)
                out[c * HW + p] = r[c];
        }
    }
}

extern "C" void kernel_launch(void* const* d_in, const int* in_sizes, int n_in,
                              void* d_out, int out_size, void* d_ws, size_t ws_size,
                              hipStream_t stream) {
    const float* inp = (const float*)d_in[0];
    const float* dep = (const float*)d_in[1];
    const float* alb = (const float*)d_in[2];
    const float* nrm = (const float*)d_in[3];
    float* out = (float*)d_out;
    dim3 grid((WW + OUTW - 1) / OUTW, HH / (RPB * WPB));   // 18 x 128, 256-thr blocks
    ls_sep_kernel<<<grid, dim3(WPB * 64), 0, stream>>>(inp, dep, alb, nrm, out);
}